// Round 9
// baseline (576.905 us; speedup 1.0000x reference)
//
#include <hip/hip_runtime.h>
#include <hip/hip_bf16.h>

// B=64, D=1024, M=1024, DMODEL=1024, PRED_LEN=96
//   hp[b,i,f] = sum_c h[b,i,c]*pw[f,c] + pb[f]
//   P [b,i,f] = sum_m u[i,m]*lam[b,f,m]
//   diag[b,i] = sum_f hp[b,i,f]*P[b,i,f];  out[b,i,:] = diag[b,i] + bias[i]
//
// fused_diag reads h/lam DIRECTLY as f32 via global_load_lds. f32 LDS tile is
// 16B-slot XOR-swizzled (slot ^= row&7) -> 2-way (free) bank access on the
// 2x ds_read_b128 frag reads. pw/u pre-converted bf16, single-buffered LDS.
// f32->bf16 on the LDS->reg frag path. LDS 80KB -> 2 blocks/CU.

#define D_    1024
#define BATCH 64
#define PRED  96

typedef __attribute__((ext_vector_type(8))) short  bf16x8;
typedef __attribute__((ext_vector_type(4))) float  f32x4;
typedef __attribute__((ext_vector_type(4))) ushort us4;

__device__ __forceinline__ ushort f2bf(float f){
  union { __hip_bfloat16 b; ushort u; } cv;
  cv.b = __float2bfloat16(f);
  return cv.u;
}
__device__ __forceinline__ float bf2f(ushort v){
  union { ushort u; __hip_bfloat16 b; } cv;
  cv.u = v;
  return __bfloat162float(cv.b);
}

// bijective XCD swizzle (m204 form)
__device__ __forceinline__ int xcd_swz(int orig, int nwg){
  int q = nwg >> 3, r = nwg & 7;
  int x = orig & 7, o = orig >> 3;
  return (x < r ? x*(q+1) : r*(q+1) + (x-r)*q) + o;
}

// async global->LDS, 16B per lane; LDS dest = wave-uniform base + lane*16
__device__ __forceinline__ void gload16(const ushort* g, ushort* l){
  __builtin_amdgcn_global_load_lds(
      (const __attribute__((address_space(1))) void*)g,
      (__attribute__((address_space(3))) void*)l, 16, 0, 0);
}
__device__ __forceinline__ void gload16f(const float* g, float* l){
  __builtin_amdgcn_global_load_lds(
      (const __attribute__((address_space(1))) void*)g,
      (__attribute__((address_space(3))) void*)l, 16, 0, 0);
}

// ------- f32 -> bf16 convert (tiny u/pw only) -------
__global__ __launch_bounds__(256) void cvt_bf16(const float* __restrict__ in,
                                                ushort* __restrict__ out, int n4){
  int stride = (int)gridDim.x * 256;
  for (int i = (int)blockIdx.x*256 + (int)threadIdx.x; i < n4; i += stride){
    f32x4 a = *((const f32x4*)in + i);
    us4 o;
    o.x = f2bf(a.x); o.y = f2bf(a.y); o.z = f2bf(a.z); o.w = f2bf(a.w);
    *(us4*)(out + (size_t)i*4) = o;
  }
}

// ---- staging: f32 tile 128x64, 16B-slot swizzle:
//      LDS[row][slot] = G[row][slot ^ (row&7)]   (slot = 4 f32 = 16B)
// per wave: 8 issues x (64 lanes x 16B) = 4 rows/issue; linear LDS dest.
__device__ __forceinline__ void issue_f32(const float* pan, int toff, float* ldst,
                                          int wv, int frow, int fsw){
  #pragma unroll
  for (int q = 0; q < 8; ++q){
    gload16f(pan + toff + (size_t)(q*16 + frow)*D_ + fsw, ldst + (q*16 + wv*4)*64);
  }
}
// ---- staging: bf16 tile 128x64 (16B = 8-bf16 chunk swizzle), 4 issues/wave
__device__ __forceinline__ void issue_bf(const ushort* pan, int toff, ushort* ldst,
                                         int wv, int srow, int scol){
  #pragma unroll
  for (int q = 0; q < 4; ++q){
    int r0 = q*32 + wv*8;
    gload16(pan + toff + (size_t)(r0 + srow)*D_ + scol, ldst + r0*64);
  }
}

// ---- frag reads (XOR back the swizzle) ----
__device__ __forceinline__ bf16x8 frag_bf(const ushort* sbuf, int r, int cb){
  return *(const bf16x8*)(sbuf + r*64 + ((cb ^ (r & 7)) << 3));
}
__device__ __forceinline__ bf16x8 frag_f32(const float* sbuf, int r, int cb){
  int g = r & 7;
  const float* p0 = sbuf + r*64 + (((2*cb    ) ^ g) << 2);  // G[r][8cb..8cb+3]
  const float* p1 = sbuf + r*64 + (((2*cb + 1) ^ g) << 2);  // G[r][8cb+4..8cb+7]
  f32x4 lo = *(const f32x4*)p0;
  f32x4 hi = *(const f32x4*)p1;
  bf16x8 f;
  f[0]=(short)f2bf(lo.x); f[1]=(short)f2bf(lo.y); f[2]=(short)f2bf(lo.z); f[3]=(short)f2bf(lo.w);
  f[4]=(short)f2bf(hi.x); f[5]=(short)f2bf(hi.y); f[6]=(short)f2bf(hi.z); f[7]=(short)f2bf(hi.w);
  return f;
}

// ---- one full 1024-deep contraction; F32A: which MFMA operand is the f32 side.
// vmcnt ledger (per phase, FIFO): issue B(t+1)[4] then F(t+2)[8]; at phase start
// outstanding = [F(t)8, B(t)4, F(t+1)8] -> vmcnt(8) drains F(t)+B(t).
template<int F32A>
__device__ __forceinline__ void gemm_loop(const float* PF, const ushort* PB,
    float* sF0, float* sF1, ushort* sG, f32x4 (&acc)[4][4],
    int wr, int wc, int lane, int wv, int frow, int fsw, int srow, int scol)
{
  issue_f32(PF, 0,  sF0, wv, frow, fsw);
  issue_bf (PB, 0,  sG,  wv, srow, scol);
  issue_f32(PF, 64, sF1, wv, frow, fsw);
  for (int t = 0; t < 16; ++t){
    float* sFc = (t & 1) ? sF1 : sF0;
    if (t < 15) asm volatile("s_waitcnt vmcnt(8)" ::: "memory");
    else        asm volatile("s_waitcnt vmcnt(0)" ::: "memory");
    __builtin_amdgcn_s_barrier();
    bf16x8 af[2][4], bfr[2][4];
    #pragma unroll
    for (int kk = 0; kk < 2; ++kk){
      int cb = kk*4 + (lane >> 4);
      #pragma unroll
      for (int x = 0; x < 4; ++x){
        int rr = x*16 + (lane & 15);
        if (F32A){
          af [kk][x] = frag_f32(sFc, wr*64 + rr, cb);
          bfr[kk][x] = frag_bf (sG,  wc*64 + rr, cb);
        } else {
          af [kk][x] = frag_bf (sG,  wr*64 + rr, cb);
          bfr[kk][x] = frag_f32(sFc, wc*64 + rr, cb);
        }
      }
    }
    asm volatile("s_waitcnt lgkmcnt(0)" ::: "memory");
    __builtin_amdgcn_sched_barrier(0);
    __builtin_amdgcn_s_barrier();
    if (t < 15) issue_bf (PB, (t+1)*64, sG,  wv, srow, scol);
    if (t < 14) issue_f32(PF, (t+2)*64, sFc, wv, frow, fsw);
    __builtin_amdgcn_s_setprio(1);
    #pragma unroll
    for (int kk = 0; kk < 2; ++kk)
      #pragma unroll
      for (int x = 0; x < 4; ++x)
        #pragma unroll
        for (int y = 0; y < 4; ++y)
          acc[x][y] = __builtin_amdgcn_mfma_f32_16x16x32_bf16(
                          af[kk][x], bfr[kk][y], acc[x][y], 0, 0, 0);
    __builtin_amdgcn_s_setprio(0);
  }
}

// ---------------- fused: hp-tile GEMM + P-tile GEMM + diag epilogue ----------------
__global__ __launch_bounds__(256, 2) void fused_diag(
    const float* __restrict__ h, const ushort* __restrict__ pwbf,
    const ushort* __restrict__ ubf, const float* __restrict__ lam,
    const float* __restrict__ pb, float* __restrict__ partial)
{
  __shared__ float  sF[2][128*64];   // 64 KB: f32 operand, double-buffered
  __shared__ ushort sG[128*64];      // 16 KB: bf16 operand, single-buffered
  int bid = xcd_swz((int)blockIdx.x, (int)gridDim.x);
  int bl = bid >> 6;                 // batch
  int t_ = bid & 63;
  int it = t_ >> 3, ft = t_ & 7;
  const float*  PanH = h    + ((size_t)bl << 20) + (size_t)(it*128) * D_;
  const ushort* PanW = pwbf + (size_t)(ft*128) * D_;
  const ushort* PanU = ubf  + (size_t)(it*128) * D_;
  const float*  PanL = lam  + ((size_t)bl << 20) + (size_t)(ft*128) * D_;
  int tid = threadIdx.x, lane = tid & 63, wv = tid >> 6;
  int wr = wv >> 1, wc = wv & 1;
  // bf16-side staging map (16B = 8-bf16 chunks)
  int srow = lane >> 3;
  int scol = (((lane & 7) ^ srow) << 3);
  // f32-side staging map: lane -> (row = wv*4 + lane>>4, slot = lane&15);
  // source slot pre-swizzled: slot_src = slot ^ (row&7)  (16 ≡ 0 mod 8 -> const/lane)
  int frow = wv*4 + (lane >> 4);
  int fsw  = (((lane & 15) ^ (frow & 7)) << 2);   // f32 units

  f32x4 acc[4][4];
  #pragma unroll
  for (int x = 0; x < 4; ++x)
    #pragma unroll
    for (int y = 0; y < 4; ++y) acc[x][y] = (f32x4){0.f,0.f,0.f,0.f};

  // ---- loop 1: hp-tile = h @ pw^T  (h = f32 A-side; pw = bf16 B-side) ----
  gemm_loop<1>(PanH, PanW, sF[0], sF[1], sG, acc, wr, wc, lane, wv, frow, fsw, srow, scol);

  // pack hp (+pb) to bf16 in registers; reset acc for loop 2
  us4 hp_pk[4][4];
  #pragma unroll
  for (int y = 0; y < 4; ++y){
    int gk = ft*128 + wc*64 + y*16 + (lane & 15);
    float pbv = pb[gk];
    #pragma unroll
    for (int x = 0; x < 4; ++x){
      us4 p;
      p.x = f2bf(acc[x][y][0] + pbv); p.y = f2bf(acc[x][y][1] + pbv);
      p.z = f2bf(acc[x][y][2] + pbv); p.w = f2bf(acc[x][y][3] + pbv);
      hp_pk[x][y] = p;
      acc[x][y] = (f32x4){0.f,0.f,0.f,0.f};
    }
  }

  // ---- loop 2: P-tile = u @ lam^T  (u = bf16 A-side; lam = f32 B-side) ----
  gemm_loop<0>(PanL, PanU, sF[0], sF[1], sG, acc, wr, wc, lane, wv, frow, fsw, srow, scol);

  // ---- epilogue: ps = rowsum over this wave's 64 cols of hp .* P ----
  f32x4 ps[4];
  #pragma unroll
  for (int x = 0; x < 4; ++x) ps[x] = (f32x4){0.f,0.f,0.f,0.f};
  #pragma unroll
  for (int y = 0; y < 4; ++y)
    #pragma unroll
    for (int x = 0; x < 4; ++x){
      ps[x][0] += bf2f(hp_pk[x][y].x) * acc[x][y][0];
      ps[x][1] += bf2f(hp_pk[x][y].y) * acc[x][y][1];
      ps[x][2] += bf2f(hp_pk[x][y].z) * acc[x][y][2];
      ps[x][3] += bf2f(hp_pk[x][y].w) * acc[x][y][3];
    }
  // butterfly over the 16 cols (lane bits 0..3); preserves row group (lane>>4)
  #pragma unroll
  for (int x = 0; x < 4; ++x)
    #pragma unroll
    for (int r = 0; r < 4; ++r){
      float v = ps[x][r];
      #pragma unroll
      for (int mm = 1; mm < 16; mm <<= 1) v += __shfl_xor(v, mm, 64);
      ps[x][r] = v;
    }
  // deterministic partial strips: strip = ft*2 + wc  (16 strips)
  if ((lane & 15) == 0){
    int strip = ft*2 + wc;
    float* pdst = partial + (size_t)strip*(BATCH*D_) + (size_t)bl*D_;
    #pragma unroll
    for (int x = 0; x < 4; ++x){
      int gi0 = it*128 + wr*64 + x*16 + (lane >> 4)*4;
      #pragma unroll
      for (int r = 0; r < 4; ++r) pdst[gi0 + r] = ps[x][r];
    }
  }
}

// ---------------- K3: diag = sum(strips) + bias; broadcast to 96 ----------------
__global__ __launch_bounds__(128) void bcast_out(
    const float* __restrict__ partial, const float* __restrict__ bias,
    float* __restrict__ out)
{
  int row = blockIdx.x;             // b*1024 + i
  int i = row & (D_-1);
  float s = bias[i];
  #pragma unroll
  for (int st = 0; st < 16; ++st) s += partial[(size_t)st*(BATCH*D_) + row];
  if (threadIdx.x < PRED) out[(size_t)row*PRED + threadIdx.x] = s;
}

// ---------------- emergency path: no workspace needed (slow, correct) ----------------
__global__ __launch_bounds__(256) void emergency_fused(
    const float* __restrict__ h, const float* __restrict__ lam,
    const float* __restrict__ uu, const float* __restrict__ bias,
    const float* __restrict__ pw, const float* __restrict__ pb,
    float* __restrict__ out)
{
  int b = blockIdx.x >> 10;
  int i = blockIdx.x & (D_-1);
  __shared__ float hps[D_];
  __shared__ float red[4];
  __shared__ float dv;
  const float* hrow = h + ((size_t)b << 20) + (size_t)i*D_;
  for (int f = threadIdx.x; f < D_; f += 256){
    const float* pwr = pw + (size_t)f*D_;
    float s = pb[f];
    for (int c = 0; c < D_; ++c) s += hrow[c]*pwr[c];
    hps[f] = s;
  }
  __syncthreads();
  const float* urow = uu + (size_t)i*D_;
  float d = 0.f;
  for (int f = threadIdx.x; f < D_; f += 256){
    const float* lr = lam + ((size_t)b << 20) + (size_t)f*D_;
    float p = 0.f;
    for (int m = 0; m < D_; ++m) p += lr[m]*urow[m];
    d += hps[f]*p;
  }
  for (int off = 32; off; off >>= 1) d += __shfl_down(d, off, 64);
  if ((threadIdx.x & 63) == 0) red[threadIdx.x >> 6] = d;
  __syncthreads();
  if (threadIdx.x == 0) dv = red[0]+red[1]+red[2]+red[3] + bias[i];
  __syncthreads();
  if (threadIdx.x < PRED) out[(size_t)blockIdx.x*PRED + threadIdx.x] = dv;
}

extern "C" void kernel_launch(void* const* d_in, const int* in_sizes, int n_in,
                              void* d_out, int out_size, void* d_ws, size_t ws_size,
                              hipStream_t stream) {
  const float* h    = (const float*)d_in[0];
  const float* lam  = (const float*)d_in[1];
  const float* uu   = (const float*)d_in[2];
  const float* bias = (const float*)d_in[3];
  const float* pw   = (const float*)d_in[4];
  const float* pb   = (const float*)d_in[5];
  float* out = (float*)d_out;

  const size_t MB = 1ull << 20;

  if (ws_size >= 8*MB) {
    float*  partial = (float*)d_ws;                       // 4 MB
    ushort* u_bf    = (ushort*)((char*)d_ws + 4*MB);      // 2 MB
    ushort* pw_bf   = (ushort*)((char*)d_ws + 6*MB);      // 2 MB

    cvt_bf16<<<dim3(512), dim3(256), 0, stream>>>(uu, u_bf, 262144);
    cvt_bf16<<<dim3(512), dim3(256), 0, stream>>>(pw, pw_bf, 262144);
    fused_diag<<<dim3(BATCH*64), dim3(256), 0, stream>>>(h, pw_bf, u_bf, lam, pb, partial);
    bcast_out<<<dim3(BATCH*D_), dim3(128), 0, stream>>>(partial, bias, out);
  } else {
    emergency_fused<<<dim3(BATCH*D_), dim3(256), 0, stream>>>(h, lam, uu, bias, pw, pb, out);
  }
}